// Round 1
// baseline (6600.682 us; speedup 1.0000x reference)
//
#include <hip/hip_runtime.h>
#include <hip/hip_bf16.h>
#include <math.h>

// Problem constants
constexpr int Bc = 4;
constexpr int Sc = 2048;
constexpr int Dc = 512;
constexpr int Hc = 8;
constexpr int DHc = 64;      // head dim
constexpr int Lc = 4;
constexpr int DFFc = 2048;
constexpr int CWc = 128;
constexpr int Tc = Bc * Sc;  // 8192 tokens
constexpr int QKVW = 3 * Dc; // 1536

// ---------------------------------------------------------------------------
// Embed: h[t,d] = x[t,0]*W_in[d,0] + x[t,1]*W_in[d,1] + b_in[d] + pos[s,d]
// ---------------------------------------------------------------------------
__global__ __launch_bounds__(256) void k_embed(const float* __restrict__ x,
                                               const float* __restrict__ W_in,
                                               const float* __restrict__ b_in,
                                               const float* __restrict__ pos,
                                               float* __restrict__ h) {
  int idx = blockIdx.x * 256 + threadIdx.x;  // over T*D
  int t = idx >> 9;          // /512
  int d = idx & 511;
  int s = t & (Sc - 1);      // t % S
  h[idx] = x[t * 2 + 0] * W_in[d * 2 + 0] + x[t * 2 + 1] * W_in[d * 2 + 1] +
           b_in[d] + pos[(size_t)s * Dc + d];
}

// ---------------------------------------------------------------------------
// GEMM: C[m,n] = sum_k A[m,k] * W[n,k] + bias[n]  (+ epilogue)
//   MODE 0: plain (+bias)
//   MODE 1: + res[m*N + n]   (residual add; only used when N == D)
//   MODE 2: exact GELU
// BM=BN=64, BK=16, 256 threads, 4x4 microtile.
// ---------------------------------------------------------------------------
template <int MODE>
__global__ __launch_bounds__(256) void k_gemm(const float* __restrict__ A,
                                              const float* __restrict__ W,
                                              const float* __restrict__ bias,
                                              const float* __restrict__ res,
                                              float* __restrict__ C,
                                              int M, int N, int K) {
  __shared__ float As[16][65];  // [k][row]
  __shared__ float Ws[16][65];  // [k][col]
  const int m0 = blockIdx.y * 64;
  const int n0 = blockIdx.x * 64;
  const int tid = threadIdx.x;
  const int tx = tid & 15;   // col group
  const int ty = tid >> 4;   // row group
  const int lc = tid & 15;   // k index for loads
  const int lr = tid >> 4;   // row 0..15 (4 passes)

  const float* Ap = A + (size_t)m0 * K;
  const float* Wp = W + (size_t)n0 * K;

  float acc[4][4] = {};

  for (int k0 = 0; k0 < K; k0 += 16) {
#pragma unroll
    for (int pp = 0; pp < 4; ++pp) {
      int r = lr + pp * 16;
      As[lc][r] = Ap[(size_t)r * K + k0 + lc];
      Ws[lc][r] = Wp[(size_t)r * K + k0 + lc];
    }
    __syncthreads();
#pragma unroll
    for (int kk = 0; kk < 16; ++kk) {
      float a0 = As[kk][ty * 4 + 0];
      float a1 = As[kk][ty * 4 + 1];
      float a2 = As[kk][ty * 4 + 2];
      float a3 = As[kk][ty * 4 + 3];
      float b0 = Ws[kk][tx * 4 + 0];
      float b1 = Ws[kk][tx * 4 + 1];
      float b2 = Ws[kk][tx * 4 + 2];
      float b3 = Ws[kk][tx * 4 + 3];
      acc[0][0] += a0 * b0; acc[0][1] += a0 * b1; acc[0][2] += a0 * b2; acc[0][3] += a0 * b3;
      acc[1][0] += a1 * b0; acc[1][1] += a1 * b1; acc[1][2] += a1 * b2; acc[1][3] += a1 * b3;
      acc[2][0] += a2 * b0; acc[2][1] += a2 * b1; acc[2][2] += a2 * b2; acc[2][3] += a2 * b3;
      acc[3][0] += a3 * b0; acc[3][1] += a3 * b1; acc[3][2] += a3 * b2; acc[3][3] += a3 * b3;
    }
    __syncthreads();
  }

#pragma unroll
  for (int i = 0; i < 4; ++i) {
    int m = m0 + ty * 4 + i;
#pragma unroll
    for (int j = 0; j < 4; ++j) {
      int n = n0 + tx * 4 + j;
      float v = acc[i][j] + bias[n];
      if (MODE == 1) v += res[(size_t)m * N + n];
      if (MODE == 2) v = 0.5f * v * (1.0f + erff(v * 0.70710678118654752f));
      C[(size_t)m * N + n] = v;
    }
  }
}

// ---------------------------------------------------------------------------
// Windowed causal attention. qkv layout: [T][1536] = [q(512) | k(512) | v(512)],
// each section is (H, dh) with head hh at offset hh*64.
// One wave per (b, hh, q); 4 waves per block.
// ---------------------------------------------------------------------------
__global__ __launch_bounds__(256) void k_attn(const float* __restrict__ qkv,
                                              float* __restrict__ o) {
  __shared__ float qs[4][64];
  __shared__ float ps[4][132];
  const int wid = threadIdx.x >> 6;
  const int lane = threadIdx.x & 63;
  const int gq = blockIdx.x * 4 + wid;   // over B*H*S = 65536
  const int b = gq >> 14;                // / (H*S)
  const int hh = (gq >> 11) & 7;
  const int q = gq & 2047;

  const float* qb = qkv + (size_t)(b * Sc + q) * QKVW + hh * DHc;
  qs[wid][lane] = qb[lane];
  __syncthreads();

  const int kstart = max(0, q - CWc);
  const int nk = q - kstart + 1;  // <= 129

  const float* kb = qkv + (size_t)(b * Sc + kstart) * QKVW + Dc + hh * DHc;

  float s0 = -1e30f, s1 = -1e30f, s2 = -1e30f;
#pragma unroll
  for (int c = 0; c < 3; ++c) {
    int j = lane + c * 64;
    if (j < nk) {
      const float* kr = kb + (size_t)j * QKVW;
      float acc = 0.0f;
#pragma unroll
      for (int d = 0; d < 64; ++d) acc += qs[wid][d] * kr[d];
      float sv = acc * 0.125f;  // 1/sqrt(64)
      if (c == 0) s0 = sv;
      if (c == 1) s1 = sv;
      if (c == 2) s2 = sv;
    }
  }
  float mx = fmaxf(fmaxf(s0, s1), s2);
#pragma unroll
  for (int off = 32; off; off >>= 1) mx = fmaxf(mx, __shfl_xor(mx, off));

  float sum = 0.0f;
  {
    int j0 = lane;
    if (j0 < nk) { float e = expf(s0 - mx); ps[wid][j0] = e; sum += e; }
    int j1 = lane + 64;
    if (j1 < nk) { float e = expf(s1 - mx); ps[wid][j1] = e; sum += e; }
    int j2 = lane + 128;
    if (j2 < nk) { float e = expf(s2 - mx); ps[wid][j2] = e; sum += e; }
  }
#pragma unroll
  for (int off = 32; off; off >>= 1) sum += __shfl_xor(sum, off);
  __syncthreads();

  const float inv = 1.0f / sum;
  const float* vb = qkv + (size_t)(b * Sc + kstart) * QKVW + 2 * Dc + hh * DHc + lane;
  float acc = 0.0f;
  for (int j = 0; j < nk; ++j) acc += ps[wid][j] * vb[(size_t)j * QKVW];
  o[(size_t)(b * Sc + q) * Dc + hh * DHc + lane] = acc * inv;
}

// ---------------------------------------------------------------------------
// LayerNorm over D=512, one wave per token.
// ---------------------------------------------------------------------------
__global__ __launch_bounds__(256) void k_ln(const float* __restrict__ in,
                                            const float* __restrict__ g,
                                            const float* __restrict__ bta,
                                            float* __restrict__ out) {
  const int wid = threadIdx.x >> 6;
  const int lane = threadIdx.x & 63;
  const int t = blockIdx.x * 4 + wid;
  const float* row = in + (size_t)t * Dc;
  float v[8];
  float sum = 0.0f, sq = 0.0f;
#pragma unroll
  for (int i = 0; i < 8; ++i) {
    float xv = row[lane + i * 64];
    v[i] = xv;
    sum += xv;
    sq += xv * xv;
  }
#pragma unroll
  for (int off = 32; off; off >>= 1) {
    sum += __shfl_xor(sum, off);
    sq += __shfl_xor(sq, off);
  }
  float m = sum * (1.0f / 512.0f);
  float var = sq * (1.0f / 512.0f) - m * m;
  float rstd = rsqrtf(var + 1e-5f);
  float* orow = out + (size_t)t * Dc;
#pragma unroll
  for (int i = 0; i < 8; ++i) {
    int d = lane + i * 64;
    orow[d] = (v[i] - m) * rstd * g[d] + bta[d];
  }
}

// ---------------------------------------------------------------------------
// Head: out4 = h @ W_head^T + b_head; mu = out4[:, :2], ls = clip(out4[:, 2:4])
// d_out layout: [0..T*2) = mu, [T*2..T*4) = log_sigma
// ---------------------------------------------------------------------------
__global__ __launch_bounds__(256) void k_head(const float* __restrict__ h,
                                              const float* __restrict__ Wh,
                                              const float* __restrict__ bh,
                                              float* __restrict__ outp) {
  const int wid = threadIdx.x >> 6;
  const int lane = threadIdx.x & 63;
  const int t = blockIdx.x * 4 + wid;
  const float* row = h + (size_t)t * Dc;
  float a0 = 0, a1 = 0, a2 = 0, a3 = 0;
#pragma unroll
  for (int i = 0; i < 8; ++i) {
    int d = lane + i * 64;
    float xv = row[d];
    a0 += xv * Wh[0 * Dc + d];
    a1 += xv * Wh[1 * Dc + d];
    a2 += xv * Wh[2 * Dc + d];
    a3 += xv * Wh[3 * Dc + d];
  }
#pragma unroll
  for (int off = 32; off; off >>= 1) {
    a0 += __shfl_xor(a0, off);
    a1 += __shfl_xor(a1, off);
    a2 += __shfl_xor(a2, off);
    a3 += __shfl_xor(a3, off);
  }
  if (lane == 0) {
    float o0 = a0 + bh[0];
    float o1 = a1 + bh[1];
    float o2 = a2 + bh[2];
    float o3 = a3 + bh[3];
    outp[(size_t)t * 2 + 0] = o0;
    outp[(size_t)t * 2 + 1] = o1;
    float c2 = fminf(fmaxf(o2, -6.0f), 1.5f);
    float c3 = fminf(fmaxf(o3, -6.0f), 1.5f);
    outp[(size_t)Tc * 2 + (size_t)t * 2 + 0] = c2;
    outp[(size_t)Tc * 2 + (size_t)t * 2 + 1] = c3;
  }
}

// ---------------------------------------------------------------------------
extern "C" void kernel_launch(void* const* d_in, const int* in_sizes, int n_in,
                              void* d_out, int out_size, void* d_ws, size_t ws_size,
                              hipStream_t stream) {
  const float* x    = (const float*)d_in[0];
  const float* W_in = (const float*)d_in[1];
  const float* b_in = (const float*)d_in[2];
  const float* pos  = (const float*)d_in[3];
  const float* Wqkv = (const float*)d_in[4];
  const float* bqkv = (const float*)d_in[5];
  const float* Wo   = (const float*)d_in[6];
  const float* bo   = (const float*)d_in[7];
  const float* W1   = (const float*)d_in[8];
  const float* b1   = (const float*)d_in[9];
  const float* W2   = (const float*)d_in[10];
  const float* b2   = (const float*)d_in[11];
  const float* ln1g = (const float*)d_in[12];
  const float* ln1b = (const float*)d_in[13];
  const float* ln2g = (const float*)d_in[14];
  const float* ln2b = (const float*)d_in[15];
  const float* Wh   = (const float*)d_in[16];
  const float* bh   = (const float*)d_in[17];
  float* out = (float*)d_out;

  // Workspace layout (floats):
  //   h    : T*D      = 4,194,304   (16 MB)
  //   t2   : T*D      = 4,194,304   (16 MB)  pre-LN buffer
  //   fb   : T*D      = 4,194,304   (16 MB)  attn-out / FF chunk (2048*2048)
  //   qkvb : T*3D     = 12,582,912  (48 MB)
  // total ~96 MB
  float* h    = (float*)d_ws;
  float* t2   = h + (size_t)Tc * Dc;
  float* fb   = t2 + (size_t)Tc * Dc;
  float* qkvb = fb + (size_t)Tc * Dc;

  k_embed<<<(Tc * Dc) / 256, 256, 0, stream>>>(x, W_in, b_in, pos, h);

  for (int l = 0; l < Lc; ++l) {
    const float* Wqkv_l = Wqkv + (size_t)l * QKVW * Dc;
    const float* bqkv_l = bqkv + (size_t)l * QKVW;
    const float* Wo_l = Wo + (size_t)l * Dc * Dc;
    const float* bo_l = bo + (size_t)l * Dc;
    const float* W1_l = W1 + (size_t)l * DFFc * Dc;
    const float* b1_l = b1 + (size_t)l * DFFc;
    const float* W2_l = W2 + (size_t)l * Dc * DFFc;
    const float* b2_l = b2 + (size_t)l * Dc;

    // qkv = h @ Wqkv^T + bqkv
    k_gemm<0><<<dim3(QKVW / 64, Tc / 64), 256, 0, stream>>>(
        h, Wqkv_l, bqkv_l, nullptr, qkvb, Tc, QKVW, Dc);

    // attention -> fb
    k_attn<<<(Bc * Hc * Sc) / 4, 256, 0, stream>>>(qkvb, fb);

    // t2 = fb @ Wo^T + bo + h
    k_gemm<1><<<dim3(Dc / 64, Tc / 64), 256, 0, stream>>>(
        fb, Wo_l, bo_l, h, t2, Tc, Dc, Dc);

    // h = LN1(t2)
    k_ln<<<Tc / 4, 256, 0, stream>>>(t2, ln1g + (size_t)l * Dc, ln1b + (size_t)l * Dc, h);

    // FF in 4 token-chunks of 2048
    for (int c = 0; c < 4; ++c) {
      const float* hc = h + (size_t)c * 2048 * Dc;
      float* t2c = t2 + (size_t)c * 2048 * Dc;
      // fb = gelu(hc @ W1^T + b1)   (2048 x 2048)
      k_gemm<2><<<dim3(DFFc / 64, 2048 / 64), 256, 0, stream>>>(
          hc, W1_l, b1_l, nullptr, fb, 2048, DFFc, Dc);
      // t2c = fb @ W2^T + b2 + hc   (2048 x 512)
      k_gemm<1><<<dim3(Dc / 64, 2048 / 64), 256, 0, stream>>>(
          fb, W2_l, b2_l, hc, t2c, 2048, Dc, DFFc);
    }

    // h = LN2(t2)
    k_ln<<<Tc / 4, 256, 0, stream>>>(t2, ln2g + (size_t)l * Dc, ln2b + (size_t)l * Dc, h);
  }

  k_head<<<Tc / 4, 256, 0, stream>>>(h, Wh, bh, out);
}

// Round 2
// 1157.832 us; speedup vs baseline: 5.7009x; 5.7009x over previous
//
#include <hip/hip_runtime.h>
#include <hip/hip_bf16.h>
#include <math.h>

// Problem constants
constexpr int Bc = 4;
constexpr int Sc = 2048;
constexpr int Dc = 512;
constexpr int Hc = 8;
constexpr int DHc = 64;
constexpr int Lc = 4;
constexpr int DFFc = 2048;
constexpr int Tc = Bc * Sc;   // 8192 tokens
constexpr int QKVW = 3 * Dc;  // 1536

typedef __attribute__((ext_vector_type(8))) short short8;
typedef __attribute__((ext_vector_type(4))) float f32x4;

static __device__ __forceinline__ float u16tof(unsigned int u) {
  return __uint_as_float(u << 16);
}
static __device__ __forceinline__ unsigned short ftobf(float f) {
  __hip_bfloat16 h = __float2bfloat16(f);
  return *reinterpret_cast<unsigned short*>(&h);
}
static __device__ __forceinline__ void gload_lds16(const void* g, void* l) {
  __builtin_amdgcn_global_load_lds(
      (const __attribute__((address_space(1))) void*)g,
      (__attribute__((address_space(3))) void*)l, 16, 0, 0);
}

// ---------------------------------------------------------------------------
// fp32 -> bf16 conversion (weights, once per launch)
// ---------------------------------------------------------------------------
__global__ __launch_bounds__(256) void k_f2bf(const float* __restrict__ in,
                                              unsigned short* __restrict__ out,
                                              int n) {
  int i = blockIdx.x * 256 + threadIdx.x;
  if (i < n) out[i] = ftobf(in[i]);
}

// ---------------------------------------------------------------------------
// Embed: h = x @ W_in^T + b_in + pos ; also bf16 copy
// ---------------------------------------------------------------------------
__global__ __launch_bounds__(256) void k_embed(const float* __restrict__ x,
                                               const float* __restrict__ W_in,
                                               const float* __restrict__ b_in,
                                               const float* __restrict__ pos,
                                               float* __restrict__ h,
                                               unsigned short* __restrict__ hb) {
  int idx = blockIdx.x * 256 + threadIdx.x;
  int t = idx >> 9;
  int d = idx & 511;
  int s = t & (Sc - 1);
  float v = x[t * 2 + 0] * W_in[d * 2 + 0] + x[t * 2 + 1] * W_in[d * 2 + 1] +
            b_in[d] + pos[(size_t)s * Dc + d];
  h[idx] = v;
  hb[idx] = ftobf(v);
}

// ---------------------------------------------------------------------------
// MFMA bf16 GEMM: C[m,n] = sum_k A[m,k]*W[n,k] + bias[n]  (+ epilogue)
//   MODE 0: +bias ; MODE 1: +bias+res ; MODE 2: +bias, exact GELU
//   OUTBF: 1 -> bf16 out, 0 -> fp32 out
// 128x128 tile, BK=32, 256 threads (4 waves, 2x2), mfma_f32_16x16x32_bf16.
// ---------------------------------------------------------------------------
template <int MODE, int OUTBF>
__global__ __launch_bounds__(256) void k_mgemm(const unsigned short* __restrict__ A,
                                               const unsigned short* __restrict__ W,
                                               const float* __restrict__ bias,
                                               const float* __restrict__ res,
                                               void* __restrict__ Cout,
                                               int M, int N, int K) {
  __shared__ short As[128 * 32];
  __shared__ short Bs[128 * 32];
  const int tid = threadIdx.x;
  const int lane = tid & 63;
  const int wid = tid >> 6;
  const int wm = wid >> 1;  // 0..1
  const int wn = wid & 1;   // 0..1
  const int m0 = blockIdx.y * 128;
  const int n0 = blockIdx.x * 128;

  // staging chunk geometry: chunk c (16B = 8 bf16): row = c>>2, kq = c&3
  const int r0 = tid >> 2, kq0 = (tid & 3) * 8;
  const int r1 = (tid + 256) >> 2, kq1 = ((tid + 256) & 3) * 8;
  short* lA0 = &As[(tid & ~63) * 8];
  short* lA1 = &As[((tid + 256) & ~63) * 8];
  short* lB0 = &Bs[(tid & ~63) * 8];
  short* lB1 = &Bs[((tid + 256) & ~63) * 8];

  f32x4 acc[4][4] = {};

  const int lr = lane & 15;       // row/col within fragment
  const int kg = (lane >> 4) * 8; // k-group offset (bf16 elems)

  for (int k0 = 0; k0 < K; k0 += 32) {
    gload_lds16(A + (size_t)(m0 + r0) * K + k0 + kq0, lA0);
    gload_lds16(A + (size_t)(m0 + r1) * K + k0 + kq1, lA1);
    gload_lds16(W + (size_t)(n0 + r0) * K + k0 + kq0, lB0);
    gload_lds16(W + (size_t)(n0 + r1) * K + k0 + kq1, lB1);
    __syncthreads();  // drains vmcnt before barrier

    short8 af[4], bf[4];
#pragma unroll
    for (int mi = 0; mi < 4; ++mi)
      af[mi] = *(const short8*)&As[(wm * 64 + mi * 16 + lr) * 32 + kg];
#pragma unroll
    for (int ni = 0; ni < 4; ++ni)
      bf[ni] = *(const short8*)&Bs[(wn * 64 + ni * 16 + lr) * 32 + kg];
#pragma unroll
    for (int mi = 0; mi < 4; ++mi)
#pragma unroll
      for (int ni = 0; ni < 4; ++ni)
        acc[mi][ni] = __builtin_amdgcn_mfma_f32_16x16x32_bf16(
            af[mi], bf[ni], acc[mi][ni], 0, 0, 0);
    __syncthreads();
  }

  // epilogue: C/D layout col = lane&15, row = (lane>>4)*4 + j
  const int cj = lane & 15;
  const int rj = (lane >> 4) * 4;
#pragma unroll
  for (int mi = 0; mi < 4; ++mi) {
#pragma unroll
    for (int ni = 0; ni < 4; ++ni) {
      int n = n0 + wn * 64 + ni * 16 + cj;
      float bn = bias[n];
#pragma unroll
      for (int j = 0; j < 4; ++j) {
        int m = m0 + wm * 64 + mi * 16 + rj + j;
        float v = acc[mi][ni][j] + bn;
        if (MODE == 1) v += res[(size_t)m * N + n];
        if (MODE == 2) v = 0.5f * v * (1.0f + erff(v * 0.70710678118654752f));
        if (OUTBF)
          ((unsigned short*)Cout)[(size_t)m * N + n] = ftobf(v);
        else
          ((float*)Cout)[(size_t)m * N + n] = v;
      }
    }
  }
}

// ---------------------------------------------------------------------------
// Windowed causal attention, LDS-staged. qkv bf16 [T][1536].
// Block: 4 waves = 4 consecutive queries for one (b,h).
// K/V window (<=132 rows) staged in LDS as bf16 with pad-66 banking.
// ---------------------------------------------------------------------------
__global__ __launch_bounds__(256) void k_attn(const unsigned short* __restrict__ qkv,
                                              unsigned short* __restrict__ o) {
  __shared__ unsigned short Ks[132 * 66];
  __shared__ unsigned short Vs[132 * 66];
  __shared__ float ps[4][132];

  const int tid = threadIdx.x;
  const int lane = tid & 63;
  const int wid = tid >> 6;
  const int idx = blockIdx.x;
  const int qblk = idx & 511;        // S/4
  const int hh = (idx >> 9) & 7;
  const int b = idx >> 12;
  const int q0 = qblk * 4;

  const int kstart = max(0, q0 - 128);
  const int nk = q0 + 4 - kstart;    // <= 132

  // stage K and V windows (bf16 bits, coalesced 16B loads)
  const int nchunk = nk * 8;         // 8 chunks of 8 bf16 per 64-dim row
  for (int c = tid; c < nchunk; c += 256) {
    int j = c >> 3, dq = (c & 7) * 8;
    size_t rowb = (size_t)(b * Sc + kstart + j) * QKVW;
    short8 kv = *(const short8*)&qkv[rowb + Dc + hh * DHc + dq];
    short8 vv = *(const short8*)&qkv[rowb + 2 * Dc + hh * DHc + dq];
    unsigned short* kd = &Ks[j * 66 + dq];
    unsigned short* vd = &Vs[j * 66 + dq];
#pragma unroll
    for (int i = 0; i < 4; ++i) {
      unsigned int kw = ((unsigned short)kv[2 * i]) | (((unsigned int)(unsigned short)kv[2 * i + 1]) << 16);
      unsigned int vw = ((unsigned short)vv[2 * i]) | (((unsigned int)(unsigned short)vv[2 * i + 1]) << 16);
      *(unsigned int*)&kd[2 * i] = kw;
      *(unsigned int*)&vd[2 * i] = vw;
    }
  }

  // q into registers (uniform per wave -> broadcast loads)
  const int q = q0 + wid;
  float qreg[64];
  {
    const unsigned short* qg = &qkv[(size_t)(b * Sc + q) * QKVW + hh * DHc];
#pragma unroll
    for (int t = 0; t < 8; ++t) {
      short8 v = *(const short8*)&qg[t * 8];
#pragma unroll
      for (int i = 0; i < 8; ++i) qreg[t * 8 + i] = u16tof((unsigned short)v[i]);
    }
  }
  __syncthreads();

  const int sg = max(0, q - 128);    // window start (global)
  const int jb = sg - kstart;        // window start (local)
  const int nq = q - sg + 1;         // <= 129

  // scores: lane = key slot
  float s0 = -1e30f, s1 = -1e30f, s2 = -1e30f;
#pragma unroll
  for (int c = 0; c < 3; ++c) {
    int kk = lane + c * 64;
    if (kk < nq) {
      const unsigned short* kr = &Ks[(jb + kk) * 66];
      float acc = 0.0f;
#pragma unroll
      for (int t = 0; t < 32; ++t) {
        unsigned int w = *(const unsigned int*)&kr[2 * t];
        acc += qreg[2 * t] * u16tof(w & 0xffffu) +
               qreg[2 * t + 1] * u16tof(w >> 16);
      }
      float sv = acc * 0.125f;
      if (c == 0) s0 = sv;
      if (c == 1) s1 = sv;
      if (c == 2) s2 = sv;
    }
  }
  float mx = fmaxf(fmaxf(s0, s1), s2);
#pragma unroll
  for (int off = 32; off; off >>= 1) mx = fmaxf(mx, __shfl_xor(mx, off));

  float sum = 0.0f;
  if (lane < nq)            { float e = expf(s0 - mx); ps[wid][lane] = e; sum += e; }
  if (lane + 64 < nq)       { float e = expf(s1 - mx); ps[wid][lane + 64] = e; sum += e; }
  if (lane + 128 < nq)      { float e = expf(s2 - mx); ps[wid][lane + 128] = e; sum += e; }
#pragma unroll
  for (int off = 32; off; off >>= 1) sum += __shfl_xor(sum, off);
  const float inv = 1.0f / sum;
  __syncthreads();  // ps visible wave-locally already; barrier orders LDS reuse across block

  // PV: lanes 0-31 handle even j, lanes 32-63 odd j; each lane owns d-pair
  const int dp = lane & 31;
  const int jh = lane >> 5;
  float a0 = 0.0f, a1 = 0.0f;
  for (int j = jh; j < nq; j += 2) {
    float p = ps[wid][j];
    unsigned int w = *(const unsigned int*)&Vs[(jb + j) * 66 + 2 * dp];
    a0 += p * u16tof(w & 0xffffu);
    a1 += p * u16tof(w >> 16);
  }
  a0 += __shfl_xor(a0, 32);
  a1 += __shfl_xor(a1, 32);
  if (lane < 32) {
    unsigned int pack = ((unsigned int)ftobf(a0 * inv)) |
                        (((unsigned int)ftobf(a1 * inv)) << 16);
    *(unsigned int*)&o[(size_t)(b * Sc + q) * Dc + hh * DHc + 2 * dp] = pack;
  }
}

// ---------------------------------------------------------------------------
// LayerNorm over D=512, one wave per token; fp32 + bf16 outputs.
// ---------------------------------------------------------------------------
__global__ __launch_bounds__(256) void k_ln(const float* __restrict__ in,
                                            const float* __restrict__ g,
                                            const float* __restrict__ bta,
                                            float* __restrict__ out,
                                            unsigned short* __restrict__ outb) {
  const int wid = threadIdx.x >> 6;
  const int lane = threadIdx.x & 63;
  const int t = blockIdx.x * 4 + wid;
  const float* row = in + (size_t)t * Dc;
  float v[8];
  float sum = 0.0f, sq = 0.0f;
#pragma unroll
  for (int i = 0; i < 8; ++i) {
    float xv = row[lane + i * 64];
    v[i] = xv;
    sum += xv;
    sq += xv * xv;
  }
#pragma unroll
  for (int off = 32; off; off >>= 1) {
    sum += __shfl_xor(sum, off);
    sq += __shfl_xor(sq, off);
  }
  float m = sum * (1.0f / 512.0f);
  float var = sq * (1.0f / 512.0f) - m * m;
  float rstd = rsqrtf(var + 1e-5f);
#pragma unroll
  for (int i = 0; i < 8; ++i) {
    int d = lane + i * 64;
    float ov = (v[i] - m) * rstd * g[d] + bta[d];
    out[(size_t)t * Dc + d] = ov;
    outb[(size_t)t * Dc + d] = ftobf(ov);
  }
}

// ---------------------------------------------------------------------------
// Head (fp32): mu | clipped log_sigma
// ---------------------------------------------------------------------------
__global__ __launch_bounds__(256) void k_head(const float* __restrict__ h,
                                              const float* __restrict__ Wh,
                                              const float* __restrict__ bh,
                                              float* __restrict__ outp) {
  const int wid = threadIdx.x >> 6;
  const int lane = threadIdx.x & 63;
  const int t = blockIdx.x * 4 + wid;
  const float* row = h + (size_t)t * Dc;
  float a0 = 0, a1 = 0, a2 = 0, a3 = 0;
#pragma unroll
  for (int i = 0; i < 8; ++i) {
    int d = lane + i * 64;
    float xv = row[d];
    a0 += xv * Wh[0 * Dc + d];
    a1 += xv * Wh[1 * Dc + d];
    a2 += xv * Wh[2 * Dc + d];
    a3 += xv * Wh[3 * Dc + d];
  }
#pragma unroll
  for (int off = 32; off; off >>= 1) {
    a0 += __shfl_xor(a0, off);
    a1 += __shfl_xor(a1, off);
    a2 += __shfl_xor(a2, off);
    a3 += __shfl_xor(a3, off);
  }
  if (lane == 0) {
    outp[(size_t)t * 2 + 0] = a0 + bh[0];
    outp[(size_t)t * 2 + 1] = a1 + bh[1];
    outp[(size_t)Tc * 2 + (size_t)t * 2 + 0] = fminf(fmaxf(a2 + bh[2], -6.0f), 1.5f);
    outp[(size_t)Tc * 2 + (size_t)t * 2 + 1] = fminf(fmaxf(a3 + bh[3], -6.0f), 1.5f);
  }
}

// ---------------------------------------------------------------------------
extern "C" void kernel_launch(void* const* d_in, const int* in_sizes, int n_in,
                              void* d_out, int out_size, void* d_ws, size_t ws_size,
                              hipStream_t stream) {
  const float* x    = (const float*)d_in[0];
  const float* W_in = (const float*)d_in[1];
  const float* b_in = (const float*)d_in[2];
  const float* pos  = (const float*)d_in[3];
  const float* Wqkv = (const float*)d_in[4];
  const float* bqkv = (const float*)d_in[5];
  const float* Wo   = (const float*)d_in[6];
  const float* bo   = (const float*)d_in[7];
  const float* W1   = (const float*)d_in[8];
  const float* b1   = (const float*)d_in[9];
  const float* W2   = (const float*)d_in[10];
  const float* b2   = (const float*)d_in[11];
  const float* ln1g = (const float*)d_in[12];
  const float* ln1b = (const float*)d_in[13];
  const float* ln2g = (const float*)d_in[14];
  const float* ln2b = (const float*)d_in[15];
  const float* Wh   = (const float*)d_in[16];
  const float* bh   = (const float*)d_in[17];
  float* out = (float*)d_out;

  // Workspace carve-up (~109 MB)
  char* p = (char*)d_ws;
  float* h  = (float*)p;           p += (size_t)Tc * Dc * 4;
  float* t2 = (float*)p;           p += (size_t)Tc * Dc * 4;
  unsigned short* hb  = (unsigned short*)p; p += (size_t)Tc * Dc * 2;
  unsigned short* ob  = (unsigned short*)p; p += (size_t)Tc * Dc * 2;
  unsigned short* big = (unsigned short*)p; p += (size_t)Tc * DFFc * 2;  // qkv(24MB) / ff(32MB)
  unsigned short* wqb = (unsigned short*)p; p += (size_t)Lc * QKVW * Dc * 2;
  unsigned short* wob = (unsigned short*)p; p += (size_t)Lc * Dc * Dc * 2;
  unsigned short* w1b = (unsigned short*)p; p += (size_t)Lc * DFFc * Dc * 2;
  unsigned short* w2b = (unsigned short*)p; p += (size_t)Lc * Dc * DFFc * 2;

  // weight conversion (all counts are multiples of 256)
  k_f2bf<<<Lc * QKVW * Dc / 256, 256, 0, stream>>>(Wqkv, wqb, Lc * QKVW * Dc);
  k_f2bf<<<Lc * Dc * Dc / 256, 256, 0, stream>>>(Wo, wob, Lc * Dc * Dc);
  k_f2bf<<<Lc * DFFc * Dc / 256, 256, 0, stream>>>(W1, w1b, Lc * DFFc * Dc);
  k_f2bf<<<Lc * Dc * DFFc / 256, 256, 0, stream>>>(W2, w2b, Lc * Dc * DFFc);

  k_embed<<<(Tc * Dc) / 256, 256, 0, stream>>>(x, W_in, b_in, pos, h, hb);

  for (int l = 0; l < Lc; ++l) {
    const unsigned short* wq_l = wqb + (size_t)l * QKVW * Dc;
    const unsigned short* wo_l = wob + (size_t)l * Dc * Dc;
    const unsigned short* w1_l = w1b + (size_t)l * DFFc * Dc;
    const unsigned short* w2_l = w2b + (size_t)l * Dc * DFFc;

    // qkv = hb @ Wqkv^T + bqkv  (bf16 out)
    k_mgemm<0, 1><<<dim3(QKVW / 128, Tc / 128), 256, 0, stream>>>(
        hb, wq_l, bqkv + (size_t)l * QKVW, nullptr, big, Tc, QKVW, Dc);

    // attention -> ob (bf16)
    k_attn<<<Bc * Hc * (Sc / 4), 256, 0, stream>>>(big, ob);

    // t2 = ob @ Wo^T + bo + h  (fp32 out)
    k_mgemm<1, 0><<<dim3(Dc / 128, Tc / 128), 256, 0, stream>>>(
        ob, wo_l, bo + (size_t)l * Dc, h, t2, Tc, Dc, Dc);

    // h,hb = LN1(t2)
    k_ln<<<Tc / 4, 256, 0, stream>>>(t2, ln1g + (size_t)l * Dc, ln1b + (size_t)l * Dc, h, hb);

    // big = gelu(hb @ W1^T + b1)  (bf16 out)
    k_mgemm<2, 1><<<dim3(DFFc / 128, Tc / 128), 256, 0, stream>>>(
        hb, w1_l, b1 + (size_t)l * DFFc, nullptr, big, Tc, DFFc, Dc);

    // t2 = big @ W2^T + b2 + h  (fp32 out)
    k_mgemm<1, 0><<<dim3(Dc / 128, Tc / 128), 256, 0, stream>>>(
        big, w2_l, b2 + (size_t)l * Dc, h, t2, Tc, Dc, DFFc);

    // h,hb = LN2(t2)
    k_ln<<<Tc / 4, 256, 0, stream>>>(t2, ln2g + (size_t)l * Dc, ln2b + (size_t)l * Dc, h, hb);
  }

  k_head<<<Tc / 4, 256, 0, stream>>>(h, Wh, bh, out);
}

// Round 3
// 718.067 us; speedup vs baseline: 9.1923x; 1.6124x over previous
//
#include <hip/hip_runtime.h>
#include <hip/hip_bf16.h>
#include <math.h>

// Problem constants
constexpr int Bc = 4;
constexpr int Sc = 2048;
constexpr int Dc = 512;
constexpr int Hc = 8;
constexpr int DHc = 64;
constexpr int Lc = 4;
constexpr int DFFc = 2048;
constexpr int Tc = Bc * Sc;   // 8192 tokens
constexpr int QKVW = 3 * Dc;  // 1536

typedef __attribute__((ext_vector_type(8))) short short8;
typedef __attribute__((ext_vector_type(4))) float f32x4;

static __device__ __forceinline__ float u16tof(unsigned int u) {
  return __uint_as_float(u << 16);
}
static __device__ __forceinline__ unsigned short ftobf(float f) {
  __hip_bfloat16 h = __float2bfloat16(f);
  return *reinterpret_cast<unsigned short*>(&h);
}
static __device__ __forceinline__ void gload_lds16(const void* g, void* l) {
  __builtin_amdgcn_global_load_lds(
      (const __attribute__((address_space(1))) void*)g,
      (__attribute__((address_space(3))) void*)l, 16, 0, 0);
}

// LDS chunk-swizzle helpers (16B-chunk XOR with row&7 -> conflict-free b128)
static __device__ __forceinline__ int swzK(int row, int col) {  // width 64
  return row * 64 + ((((col >> 3) ^ (row & 7)) << 3) | (col & 7));
}
static __device__ __forceinline__ int swzW(int row, int col) {  // width 192
  return row * 192 + ((((col >> 3) ^ (row & 7)) << 3) | (col & 7));
}

// ---------------------------------------------------------------------------
// fp32 -> bf16 conversion (weights, once per launch)
// ---------------------------------------------------------------------------
__global__ __launch_bounds__(256) void k_f2bf(const float* __restrict__ in,
                                              unsigned short* __restrict__ out,
                                              int n) {
  int i = blockIdx.x * 256 + threadIdx.x;
  if (i < n) out[i] = ftobf(in[i]);
}

// ---------------------------------------------------------------------------
// Embed: h = x @ W_in^T + b_in + pos ; also bf16 copy
// ---------------------------------------------------------------------------
__global__ __launch_bounds__(256) void k_embed(const float* __restrict__ x,
                                               const float* __restrict__ W_in,
                                               const float* __restrict__ b_in,
                                               const float* __restrict__ pos,
                                               float* __restrict__ h,
                                               unsigned short* __restrict__ hb) {
  int idx = blockIdx.x * 256 + threadIdx.x;
  int t = idx >> 9;
  int d = idx & 511;
  int s = t & (Sc - 1);
  float v = x[t * 2 + 0] * W_in[d * 2 + 0] + x[t * 2 + 1] * W_in[d * 2 + 1] +
            b_in[d] + pos[(size_t)s * Dc + d];
  h[idx] = v;
  hb[idx] = ftobf(v);
}

// ---------------------------------------------------------------------------
// MFMA bf16 GEMM: C[m,n] = sum_k A[m,k]*W[n,k] + bias[n]  (+ epilogue)
//   MODE 0: +bias ; MODE 1: +bias+res ; MODE 2: +bias, exact GELU
//   OUTBF: 1 -> bf16 out, 0 -> fp32 out
// 128x128 tile, BK=32, 256 threads (4 waves, 2x2), mfma_f32_16x16x32_bf16.
// ---------------------------------------------------------------------------
template <int MODE, int OUTBF>
__global__ __launch_bounds__(256) void k_mgemm(const unsigned short* __restrict__ A,
                                               const unsigned short* __restrict__ W,
                                               const float* __restrict__ bias,
                                               const float* __restrict__ res,
                                               void* __restrict__ Cout,
                                               int M, int N, int K) {
  __shared__ short As[128 * 32];
  __shared__ short Bs[128 * 32];
  const int tid = threadIdx.x;
  const int lane = tid & 63;
  const int wid = tid >> 6;
  const int wm = wid >> 1;  // 0..1
  const int wn = wid & 1;   // 0..1
  const int m0 = blockIdx.y * 128;
  const int n0 = blockIdx.x * 128;

  const int r0 = tid >> 2, kq0 = (tid & 3) * 8;
  const int r1 = (tid + 256) >> 2, kq1 = ((tid + 256) & 3) * 8;
  short* lA0 = &As[(tid & ~63) * 8];
  short* lA1 = &As[((tid + 256) & ~63) * 8];
  short* lB0 = &Bs[(tid & ~63) * 8];
  short* lB1 = &Bs[((tid + 256) & ~63) * 8];

  f32x4 acc[4][4] = {};

  const int lr = lane & 15;
  const int kg = (lane >> 4) * 8;

  for (int k0 = 0; k0 < K; k0 += 32) {
    gload_lds16(A + (size_t)(m0 + r0) * K + k0 + kq0, lA0);
    gload_lds16(A + (size_t)(m0 + r1) * K + k0 + kq1, lA1);
    gload_lds16(W + (size_t)(n0 + r0) * K + k0 + kq0, lB0);
    gload_lds16(W + (size_t)(n0 + r1) * K + k0 + kq1, lB1);
    __syncthreads();

    short8 af[4], bf[4];
#pragma unroll
    for (int mi = 0; mi < 4; ++mi)
      af[mi] = *(const short8*)&As[(wm * 64 + mi * 16 + lr) * 32 + kg];
#pragma unroll
    for (int ni = 0; ni < 4; ++ni)
      bf[ni] = *(const short8*)&Bs[(wn * 64 + ni * 16 + lr) * 32 + kg];
#pragma unroll
    for (int mi = 0; mi < 4; ++mi)
#pragma unroll
      for (int ni = 0; ni < 4; ++ni)
        acc[mi][ni] = __builtin_amdgcn_mfma_f32_16x16x32_bf16(
            af[mi], bf[ni], acc[mi][ni], 0, 0, 0);
    __syncthreads();
  }

  const int cj = lane & 15;
  const int rj = (lane >> 4) * 4;
#pragma unroll
  for (int mi = 0; mi < 4; ++mi) {
#pragma unroll
    for (int ni = 0; ni < 4; ++ni) {
      int n = n0 + wn * 64 + ni * 16 + cj;
      float bn = bias[n];
#pragma unroll
      for (int j = 0; j < 4; ++j) {
        int m = m0 + wm * 64 + mi * 16 + rj + j;
        float v = acc[mi][ni][j] + bn;
        if (MODE == 1) v += res[(size_t)m * N + n];
        if (MODE == 2) v = 0.5f * v * (1.0f + erff(v * 0.70710678118654752f));
        if (OUTBF)
          ((unsigned short*)Cout)[(size_t)m * N + n] = ftobf(v);
        else
          ((float*)Cout)[(size_t)m * N + n] = v;
      }
    }
  }
}

// ---------------------------------------------------------------------------
// Windowed causal attention, MFMA. qkv bf16 [T][1536].
// Block: 64 queries of one (b,h); 4 waves x 16 queries.
// Swapped QK^T (A=K,B=Q^T) -> lane-local softmax; P->LDS; PV (A=P,B=V^T).
// LDS: Ks[192][64], Vt[64][192], Ps[64][192], all chunk-XOR swizzled. 72KB.
// ---------------------------------------------------------------------------
__global__ __launch_bounds__(256) void k_attn(const unsigned short* __restrict__ qkv,
                                              unsigned short* __restrict__ o) {
  __shared__ unsigned short Ks[192 * 64];
  __shared__ unsigned short Vt[64 * 192];
  __shared__ unsigned short Ps[64 * 192];

  const int tid = threadIdx.x;
  const int lane = tid & 63;
  const int w = tid >> 6;
  const int idx = blockIdx.x;
  const int qb = idx & 31;
  const int hh = (idx >> 5) & 7;
  const int b = idx >> 8;
  const int q0 = qb * 64;
  const int kstart = max(0, q0 - 128);
  const int nk = q0 + 64 - kstart;  // 64 (qb==0) or 192

  // stage K rows (coalesced 16B, swizzled b128 LDS writes)
  for (int c = tid; c < nk * 8; c += 256) {
    int j = c >> 3, ch = c & 7;
    short8 kv = *(const short8*)&qkv[(size_t)(b * Sc + kstart + j) * QKVW + Dc + hh * DHc + ch * 8];
    *(short8*)&Ks[swzK(j, ch * 8)] = kv;
  }
  // stage V transposed: Vt[d][j]
  for (int c = tid; c < (nk >> 1) * 8; c += 256) {
    int jp = c >> 3, ch = c & 7;
    int j = jp * 2;
    const unsigned short* base =
        &qkv[(size_t)(b * Sc + kstart + j) * QKVW + 2 * Dc + hh * DHc + ch * 8];
    short8 v0 = *(const short8*)base;
    short8 v1 = *(const short8*)(base + QKVW);
#pragma unroll
    for (int i = 0; i < 8; ++i) {
      unsigned int pk = (unsigned short)v0[i] | ((unsigned int)(unsigned short)v1[i] << 16);
      *(unsigned int*)&Vt[swzW(ch * 8 + i, j)] = pk;
    }
  }
  if (nk < 192) {  // qb==0: zero Vt cols [64,192) so P*garbage can't NaN
    for (int c = tid; c < 64 * 64; c += 256) {
      int d = c >> 6, jo = c & 63;
      *(unsigned int*)&Vt[swzW(d, 64 + jo * 2)] = 0;
    }
  }

  // Q B-fragments from global (col = lane&15 = query, contiguous d)
  const int qg = q0 + w * 16 + (lane & 15);
  const int kg8 = (lane >> 4) * 8;
  const unsigned short* qp = &qkv[(size_t)(b * Sc + qg) * QKVW + hh * DHc + kg8];
  short8 bq0 = *(const short8*)qp;
  short8 bq1 = *(const short8*)(qp + 32);
  __syncthreads();

  const int jb = max(0, q0 + w * 16 - 128) - kstart;  // wave's window start (block-rel)

  // QK^T (swapped): S^T[key][q], 9 key tiles x K=64
  f32x4 sacc[9];
#pragma unroll
  for (int t = 0; t < 9; ++t) {
    int key = jb + t * 16 + (lane & 15);
    short8 a0 = *(const short8*)&Ks[swzK(key, kg8)];
    short8 a1 = *(const short8*)&Ks[swzK(key, 32 + kg8)];
    f32x4 z = {0.f, 0.f, 0.f, 0.f};
    z = __builtin_amdgcn_mfma_f32_16x16x32_bf16(a0, bq0, z, 0, 0, 0);
    sacc[t] = __builtin_amdgcn_mfma_f32_16x16x32_bf16(a1, bq1, z, 0, 0, 0);
  }

  // mask + scale + lane-local softmax (col = q is lane-local)
  const int rj = (lane >> 4) * 4;
  float mx = -1e30f;
#pragma unroll
  for (int t = 0; t < 9; ++t) {
#pragma unroll
    for (int j = 0; j < 4; ++j) {
      int kglob = kstart + jb + t * 16 + rj + j;
      bool valid = (kglob <= qg) && (kglob + 128 >= qg);
      float s = valid ? sacc[t][j] * 0.125f : -1e30f;  // cndmask also kills NaN
      sacc[t][j] = s;
      mx = fmaxf(mx, s);
    }
  }
  mx = fmaxf(mx, __shfl_xor(mx, 16));
  mx = fmaxf(mx, __shfl_xor(mx, 32));
  float sum = 0.f;
#pragma unroll
  for (int t = 0; t < 9; ++t)
#pragma unroll
    for (int j = 0; j < 4; ++j) {
      float e = __expf(sacc[t][j] - mx);
      sacc[t][j] = e;
      sum += e;
    }
  sum += __shfl_xor(sum, 16);
  sum += __shfl_xor(sum, 32);
  const float inv = 1.0f / sum;

  // write P (1/sum folded) to wave-private LDS rows
  const int prow = w * 16 + (lane & 15);
#pragma unroll
  for (int t = 0; t < 9; ++t) {
    int c0 = jb + t * 16 + rj;
    unsigned int p0 = ftobf(sacc[t][0] * inv) |
                      ((unsigned int)ftobf(sacc[t][1] * inv) << 16);
    unsigned int p1 = ftobf(sacc[t][2] * inv) |
                      ((unsigned int)ftobf(sacc[t][3] * inv) << 16);
    *(unsigned int*)&Ps[swzW(prow, c0)] = p0;
    *(unsigned int*)&Ps[swzW(prow, c0 + 2)] = p1;
  }
  // zero-fill P outside [jb, jb+144)
  {
    int g2 = (lane >> 4) * 2;
    for (int col = g2; col < jb; col += 8)
      *(unsigned int*)&Ps[swzW(prow, col)] = 0;
    for (int col = jb + 144 + g2; col < 192; col += 8)
      *(unsigned int*)&Ps[swzW(prow, col)] = 0;
  }
  // PV: O[q][d] over full staged range [0,192) (wave-local deps only)
  f32x4 oacc[4] = {};
#pragma unroll
  for (int kb = 0; kb < 6; ++kb) {
    short8 pa = *(const short8*)&Ps[swzW(prow, kb * 32 + kg8)];
#pragma unroll
    for (int dt = 0; dt < 4; ++dt) {
      short8 vb = *(const short8*)&Vt[swzW(dt * 16 + (lane & 15), kb * 32 + kg8)];
      oacc[dt] = __builtin_amdgcn_mfma_f32_16x16x32_bf16(pa, vb, oacc[dt], 0, 0, 0);
    }
  }
  // write O: col=lane&15=d within tile, row=(lane>>4)*4+j = q within 16
  const int cj = lane & 15;
#pragma unroll
  for (int j = 0; j < 4; ++j)
#pragma unroll
    for (int dt = 0; dt < 4; ++dt)
      o[(size_t)(b * Sc + q0 + w * 16 + rj + j) * Dc + hh * DHc + dt * 16 + cj] =
          ftobf(oacc[dt][j]);
}

// ---------------------------------------------------------------------------
// LayerNorm over D=512, one wave per token; fp32 + bf16 outputs.
// ---------------------------------------------------------------------------
__global__ __launch_bounds__(256) void k_ln(const float* __restrict__ in,
                                            const float* __restrict__ g,
                                            const float* __restrict__ bta,
                                            float* __restrict__ out,
                                            unsigned short* __restrict__ outb) {
  const int wid = threadIdx.x >> 6;
  const int lane = threadIdx.x & 63;
  const int t = blockIdx.x * 4 + wid;
  const float* row = in + (size_t)t * Dc;
  float v[8];
  float sum = 0.0f, sq = 0.0f;
#pragma unroll
  for (int i = 0; i < 8; ++i) {
    float xv = row[lane + i * 64];
    v[i] = xv;
    sum += xv;
    sq += xv * xv;
  }
#pragma unroll
  for (int off = 32; off; off >>= 1) {
    sum += __shfl_xor(sum, off);
    sq += __shfl_xor(sq, off);
  }
  float m = sum * (1.0f / 512.0f);
  float var = sq * (1.0f / 512.0f) - m * m;
  float rstd = rsqrtf(var + 1e-5f);
#pragma unroll
  for (int i = 0; i < 8; ++i) {
    int d = lane + i * 64;
    float ov = (v[i] - m) * rstd * g[d] + bta[d];
    out[(size_t)t * Dc + d] = ov;
    outb[(size_t)t * Dc + d] = ftobf(ov);
  }
}

// ---------------------------------------------------------------------------
// Head (fp32): mu | clipped log_sigma
// ---------------------------------------------------------------------------
__global__ __launch_bounds__(256) void k_head(const float* __restrict__ h,
                                              const float* __restrict__ Wh,
                                              const float* __restrict__ bh,
                                              float* __restrict__ outp) {
  const int wid = threadIdx.x >> 6;
  const int lane = threadIdx.x & 63;
  const int t = blockIdx.x * 4 + wid;
  const float* row = h + (size_t)t * Dc;
  float a0 = 0, a1 = 0, a2 = 0, a3 = 0;
#pragma unroll
  for (int i = 0; i < 8; ++i) {
    int d = lane + i * 64;
    float xv = row[d];
    a0 += xv * Wh[0 * Dc + d];
    a1 += xv * Wh[1 * Dc + d];
    a2 += xv * Wh[2 * Dc + d];
    a3 += xv * Wh[3 * Dc + d];
  }
#pragma unroll
  for (int off = 32; off; off >>= 1) {
    a0 += __shfl_xor(a0, off);
    a1 += __shfl_xor(a1, off);
    a2 += __shfl_xor(a2, off);
    a3 += __shfl_xor(a3, off);
  }
  if (lane == 0) {
    outp[(size_t)t * 2 + 0] = a0 + bh[0];
    outp[(size_t)t * 2 + 1] = a1 + bh[1];
    outp[(size_t)Tc * 2 + (size_t)t * 2 + 0] = fminf(fmaxf(a2 + bh[2], -6.0f), 1.5f);
    outp[(size_t)Tc * 2 + (size_t)t * 2 + 1] = fminf(fmaxf(a3 + bh[3], -6.0f), 1.5f);
  }
}

// ---------------------------------------------------------------------------
extern "C" void kernel_launch(void* const* d_in, const int* in_sizes, int n_in,
                              void* d_out, int out_size, void* d_ws, size_t ws_size,
                              hipStream_t stream) {
  const float* x    = (const float*)d_in[0];
  const float* W_in = (const float*)d_in[1];
  const float* b_in = (const float*)d_in[2];
  const float* pos  = (const float*)d_in[3];
  const float* Wqkv = (const float*)d_in[4];
  const float* bqkv = (const float*)d_in[5];
  const float* Wo   = (const float*)d_in[6];
  const float* bo   = (const float*)d_in[7];
  const float* W1   = (const float*)d_in[8];
  const float* b1   = (const float*)d_in[9];
  const float* W2   = (const float*)d_in[10];
  const float* b2   = (const float*)d_in[11];
  const float* ln1g = (const float*)d_in[12];
  const float* ln1b = (const float*)d_in[13];
  const float* ln2g = (const float*)d_in[14];
  const float* ln2b = (const float*)d_in[15];
  const float* Wh   = (const float*)d_in[16];
  const float* bh   = (const float*)d_in[17];
  float* out = (float*)d_out;

  char* p = (char*)d_ws;
  float* h  = (float*)p;           p += (size_t)Tc * Dc * 4;
  float* t2 = (float*)p;           p += (size_t)Tc * Dc * 4;
  unsigned short* hb  = (unsigned short*)p; p += (size_t)Tc * Dc * 2;
  unsigned short* ob  = (unsigned short*)p; p += (size_t)Tc * Dc * 2;
  unsigned short* big = (unsigned short*)p; p += (size_t)Tc * DFFc * 2;
  unsigned short* wqb = (unsigned short*)p; p += (size_t)Lc * QKVW * Dc * 2;
  unsigned short* wob = (unsigned short*)p; p += (size_t)Lc * Dc * Dc * 2;
  unsigned short* w1b = (unsigned short*)p; p += (size_t)Lc * DFFc * Dc * 2;
  unsigned short* w2b = (unsigned short*)p; p += (size_t)Lc * Dc * DFFc * 2;

  k_f2bf<<<Lc * QKVW * Dc / 256, 256, 0, stream>>>(Wqkv, wqb, Lc * QKVW * Dc);
  k_f2bf<<<Lc * Dc * Dc / 256, 256, 0, stream>>>(Wo, wob, Lc * Dc * Dc);
  k_f2bf<<<Lc * DFFc * Dc / 256, 256, 0, stream>>>(W1, w1b, Lc * DFFc * Dc);
  k_f2bf<<<Lc * Dc * DFFc / 256, 256, 0, stream>>>(W2, w2b, Lc * Dc * DFFc);

  k_embed<<<(Tc * Dc) / 256, 256, 0, stream>>>(x, W_in, b_in, pos, h, hb);

  for (int l = 0; l < Lc; ++l) {
    const unsigned short* wq_l = wqb + (size_t)l * QKVW * Dc;
    const unsigned short* wo_l = wob + (size_t)l * Dc * Dc;
    const unsigned short* w1_l = w1b + (size_t)l * DFFc * Dc;
    const unsigned short* w2_l = w2b + (size_t)l * Dc * DFFc;

    k_mgemm<0, 1><<<dim3(QKVW / 128, Tc / 128), 256, 0, stream>>>(
        hb, wq_l, bqkv + (size_t)l * QKVW, nullptr, big, Tc, QKVW, Dc);

    k_attn<<<Bc * Hc * (Sc / 64), 256, 0, stream>>>(big, ob);

    k_mgemm<1, 0><<<dim3(Dc / 128, Tc / 128), 256, 0, stream>>>(
        ob, wo_l, bo + (size_t)l * Dc, h, t2, Tc, Dc, Dc);

    k_ln<<<Tc / 4, 256, 0, stream>>>(t2, ln1g + (size_t)l * Dc, ln1b + (size_t)l * Dc, h, hb);

    k_mgemm<2, 1><<<dim3(DFFc / 128, Tc / 128), 256, 0, stream>>>(
        hb, w1_l, b1 + (size_t)l * DFFc, nullptr, big, Tc, DFFc, Dc);

    k_mgemm<1, 0><<<dim3(Dc / 128, Tc / 128), 256, 0, stream>>>(
        big, w2_l, b2 + (size_t)l * Dc, h, t2, Tc, Dc, DFFc);

    k_ln<<<Tc / 4, 256, 0, stream>>>(t2, ln2g + (size_t)l * Dc, ln2b + (size_t)l * Dc, h, hb);
  }

  k_head<<<Tc / 4, 256, 0, stream>>>(h, Wh, bh, out);
}

// Round 4
// 646.284 us; speedup vs baseline: 10.2133x; 1.1111x over previous
//
#include <hip/hip_runtime.h>
#include <hip/hip_bf16.h>
#include <math.h>

// Problem constants
constexpr int Bc = 4;
constexpr int Sc = 2048;
constexpr int Dc = 512;
constexpr int Hc = 8;
constexpr int DHc = 64;
constexpr int Lc = 4;
constexpr int DFFc = 2048;
constexpr int Tc = Bc * Sc;   // 8192 tokens
constexpr int QKVW = 3 * Dc;  // 1536

typedef __attribute__((ext_vector_type(8))) short short8;
typedef __attribute__((ext_vector_type(4))) float f32x4;

static __device__ __forceinline__ float u16tof(unsigned int u) {
  return __uint_as_float(u << 16);
}
static __device__ __forceinline__ unsigned short ftobf(float f) {
  __hip_bfloat16 h = __float2bfloat16(f);
  return *reinterpret_cast<unsigned short*>(&h);
}
static __device__ __forceinline__ void gload_lds16(const void* g, void* l) {
  __builtin_amdgcn_global_load_lds(
      (const __attribute__((address_space(1))) void*)g,
      (__attribute__((address_space(3))) void*)l, 16, 0, 0);
}

// LDS chunk-swizzle helpers for attention (16B-chunk XOR, conflict-free b128)
static __device__ __forceinline__ int swzK(int row, int col) {  // width 64
  return row * 64 + ((((col >> 3) ^ (row & 7)) << 3) | (col & 7));
}
static __device__ __forceinline__ int swzW(int row, int col) {  // width 192
  return row * 192 + ((((col >> 3) ^ (row & 7)) << 3) | (col & 7));
}

// ---------------------------------------------------------------------------
// fp32 -> bf16 conversion (weights, once per launch)
// ---------------------------------------------------------------------------
__global__ __launch_bounds__(256) void k_f2bf(const float* __restrict__ in,
                                              unsigned short* __restrict__ out,
                                              int n) {
  int i = blockIdx.x * 256 + threadIdx.x;
  if (i < n) out[i] = ftobf(in[i]);
}

// ---------------------------------------------------------------------------
// Embed: h = x @ W_in^T + b_in + pos ; also bf16 copy
// ---------------------------------------------------------------------------
__global__ __launch_bounds__(256) void k_embed(const float* __restrict__ x,
                                               const float* __restrict__ W_in,
                                               const float* __restrict__ b_in,
                                               const float* __restrict__ pos,
                                               float* __restrict__ h,
                                               unsigned short* __restrict__ hb) {
  int idx = blockIdx.x * 256 + threadIdx.x;
  int t = idx >> 9;
  int d = idx & 511;
  int s = t & (Sc - 1);
  float v = x[t * 2 + 0] * W_in[d * 2 + 0] + x[t * 2 + 1] * W_in[d * 2 + 1] +
            b_in[d] + pos[(size_t)s * Dc + d];
  h[idx] = v;
  hb[idx] = ftobf(v);
}

// ---------------------------------------------------------------------------
// MFMA bf16 GEMM, 2-phase double-buffered + chunk-swizzled LDS + XCD swizzle.
//   C[m,n] = sum_k A[m,k]*W[n,k] + bias[n]  (+ epilogue)
//   MODE 0: +bias ; MODE 1: +bias+res ; MODE 2: +bias, exact GELU
//   OUTBF: 1 -> bf16 out, 0 -> fp32 out
// 128x128 tile, BK=32, 256 threads (4 waves, 2x2), mfma_f32_16x16x32_bf16.
//
// LDS layout: per buffer, 512 chunks of 16B (8 bf16). Chunk (row,ch) stored at
//   p = (row>>1)*8 + ((((row&1)<<2)|ch) ^ ((row>>1)&7))
// global_load_lds writes linearly (base+lane*16), so the SOURCE global address
// is pre-permuted per lane with the inverse map; reads use the same map.
// 16-lane fragment read (rows r..r+15, ch fixed) -> all 8 bank-quads, 2-way = free.
// ---------------------------------------------------------------------------
template <int MODE, int OUTBF>
__global__ __launch_bounds__(256) void k_mgemm(const unsigned short* __restrict__ A,
                                               const unsigned short* __restrict__ W,
                                               const float* __restrict__ bias,
                                               const float* __restrict__ res,
                                               void* __restrict__ Cout,
                                               int M, int N, int K) {
  __shared__ short As[2][512 * 8];
  __shared__ short Bs[2][512 * 8];
  const int tid = threadIdx.x;
  const int lane = tid & 63;
  const int wid = tid >> 6;
  const int wm = wid >> 1;  // 0..1
  const int wn = wid & 1;   // 0..1

  // XCD-aware block swizzle (all grids used here have nwg % 8 == 0)
  const int nwg = gridDim.x * gridDim.y;
  const int bid = blockIdx.y * gridDim.x + blockIdx.x;
  const int swz = (bid & 7) * (nwg >> 3) + (bid >> 3);
  const int m0 = (swz / gridDim.x) * 128;
  const int n0 = (swz % gridDim.x) * 128;

  // staging: invert p -> (row, ch) for the two positions this thread covers
  int r0S, c0S, r1S, c1S;
  {
    int p = tid;
    int rp = p >> 3, q = (p & 7) ^ (rp & 7);
    r0S = (rp << 1) | (q >> 2);
    c0S = q & 3;
    p = tid + 256;
    rp = p >> 3;
    q = (p & 7) ^ (rp & 7);
    r1S = (rp << 1) | (q >> 2);
    c1S = q & 3;
  }
  const unsigned short* a0p = A + (size_t)(m0 + r0S) * K + c0S * 8;
  const unsigned short* a1p = A + (size_t)(m0 + r1S) * K + c1S * 8;
  const unsigned short* b0p = W + (size_t)(n0 + r0S) * K + c0S * 8;
  const unsigned short* b1p = W + (size_t)(n0 + r1S) * K + c1S * 8;
  const int d0 = (tid & ~63) * 8;          // linear LDS dest (shorts), issue 0
  const int d1 = ((tid + 256) & ~63) * 8;  // issue 1

  f32x4 acc[4][4] = {};
  const int lr = lane & 15;
  const int chr = lane >> 4;  // fragment k-block == chunk index

  // prologue: stage tile 0 into buf 0
  gload_lds16(a0p, &As[0][d0]);
  gload_lds16(a1p, &As[0][d1]);
  gload_lds16(b0p, &Bs[0][d0]);
  gload_lds16(b1p, &Bs[0][d1]);
  __syncthreads();

  const int nsteps = K >> 5;
  int buf = 0;
  for (int s = 0; s < nsteps; ++s) {
    if (s + 1 < nsteps) {  // issue next-tile loads BEFORE consuming current
      const int ko = (s + 1) << 5;
      gload_lds16(a0p + ko, &As[buf ^ 1][d0]);
      gload_lds16(a1p + ko, &As[buf ^ 1][d1]);
      gload_lds16(b0p + ko, &Bs[buf ^ 1][d0]);
      gload_lds16(b1p + ko, &Bs[buf ^ 1][d1]);
    }
    short8 af[4], bfr[4];
#pragma unroll
    for (int mi = 0; mi < 4; ++mi) {
      int row = wm * 64 + mi * 16 + lr;
      int rp = row >> 1;
      int p = rp * 8 + (((((row & 1) << 2) | chr)) ^ (rp & 7));
      af[mi] = *(const short8*)&As[buf][p * 8];
    }
#pragma unroll
    for (int ni = 0; ni < 4; ++ni) {
      int row = wn * 64 + ni * 16 + lr;
      int rp = row >> 1;
      int p = rp * 8 + (((((row & 1) << 2) | chr)) ^ (rp & 7));
      bfr[ni] = *(const short8*)&Bs[buf][p * 8];
    }
#pragma unroll
    for (int mi = 0; mi < 4; ++mi)
#pragma unroll
      for (int ni = 0; ni < 4; ++ni)
        acc[mi][ni] = __builtin_amdgcn_mfma_f32_16x16x32_bf16(
            af[mi], bfr[ni], acc[mi][ni], 0, 0, 0);
    __syncthreads();  // compiler drains vmcnt here -> next buf ready
    buf ^= 1;
  }

  // epilogue: C/D layout col = lane&15, row = (lane>>4)*4 + j
  const int cj = lane & 15;
  const int rj = (lane >> 4) * 4;
#pragma unroll
  for (int mi = 0; mi < 4; ++mi) {
#pragma unroll
    for (int ni = 0; ni < 4; ++ni) {
      int n = n0 + wn * 64 + ni * 16 + cj;
      float bn = bias[n];
#pragma unroll
      for (int j = 0; j < 4; ++j) {
        int m = m0 + wm * 64 + mi * 16 + rj + j;
        float v = acc[mi][ni][j] + bn;
        if (MODE == 1) v += res[(size_t)m * N + n];
        if (MODE == 2) v = 0.5f * v * (1.0f + erff(v * 0.70710678118654752f));
        if (OUTBF)
          ((unsigned short*)Cout)[(size_t)m * N + n] = ftobf(v);
        else
          ((float*)Cout)[(size_t)m * N + n] = v;
      }
    }
  }
}

// ---------------------------------------------------------------------------
// Windowed causal attention, MFMA. qkv bf16 [T][1536].
// Block: 64 queries of one (b,h); 4 waves x 16 queries.
// Swapped QK^T (A=K,B=Q^T) -> lane-local softmax; P->LDS; PV (A=P,B=V^T).
// ---------------------------------------------------------------------------
__global__ __launch_bounds__(256) void k_attn(const unsigned short* __restrict__ qkv,
                                              unsigned short* __restrict__ o) {
  __shared__ unsigned short Ks[192 * 64];
  __shared__ unsigned short Vt[64 * 192];
  __shared__ unsigned short Ps[64 * 192];

  const int tid = threadIdx.x;
  const int lane = tid & 63;
  const int w = tid >> 6;
  const int idx = blockIdx.x;
  const int qb = idx & 31;
  const int hh = (idx >> 5) & 7;
  const int b = idx >> 8;
  const int q0 = qb * 64;
  const int kstart = max(0, q0 - 128);
  const int nk = q0 + 64 - kstart;  // 64 (qb==0) or 192

  for (int c = tid; c < nk * 8; c += 256) {
    int j = c >> 3, ch = c & 7;
    short8 kv = *(const short8*)&qkv[(size_t)(b * Sc + kstart + j) * QKVW + Dc + hh * DHc + ch * 8];
    *(short8*)&Ks[swzK(j, ch * 8)] = kv;
  }
  for (int c = tid; c < (nk >> 1) * 8; c += 256) {
    int jp = c >> 3, ch = c & 7;
    int j = jp * 2;
    const unsigned short* base =
        &qkv[(size_t)(b * Sc + kstart + j) * QKVW + 2 * Dc + hh * DHc + ch * 8];
    short8 v0 = *(const short8*)base;
    short8 v1 = *(const short8*)(base + QKVW);
#pragma unroll
    for (int i = 0; i < 8; ++i) {
      unsigned int pk = (unsigned short)v0[i] | ((unsigned int)(unsigned short)v1[i] << 16);
      *(unsigned int*)&Vt[swzW(ch * 8 + i, j)] = pk;
    }
  }
  if (nk < 192) {
    for (int c = tid; c < 64 * 64; c += 256) {
      int d = c >> 6, jo = c & 63;
      *(unsigned int*)&Vt[swzW(d, 64 + jo * 2)] = 0;
    }
  }

  const int qg = q0 + w * 16 + (lane & 15);
  const int kg8 = (lane >> 4) * 8;
  const unsigned short* qp = &qkv[(size_t)(b * Sc + qg) * QKVW + hh * DHc + kg8];
  short8 bq0 = *(const short8*)qp;
  short8 bq1 = *(const short8*)(qp + 32);
  __syncthreads();

  const int jb = max(0, q0 + w * 16 - 128) - kstart;

  f32x4 sacc[9];
#pragma unroll
  for (int t = 0; t < 9; ++t) {
    int key = jb + t * 16 + (lane & 15);
    short8 a0 = *(const short8*)&Ks[swzK(key, kg8)];
    short8 a1 = *(const short8*)&Ks[swzK(key, 32 + kg8)];
    f32x4 z = {0.f, 0.f, 0.f, 0.f};
    z = __builtin_amdgcn_mfma_f32_16x16x32_bf16(a0, bq0, z, 0, 0, 0);
    sacc[t] = __builtin_amdgcn_mfma_f32_16x16x32_bf16(a1, bq1, z, 0, 0, 0);
  }

  const int rj = (lane >> 4) * 4;
  float mx = -1e30f;
#pragma unroll
  for (int t = 0; t < 9; ++t) {
#pragma unroll
    for (int j = 0; j < 4; ++j) {
      int kglob = kstart + jb + t * 16 + rj + j;
      bool valid = (kglob <= qg) && (kglob + 128 >= qg);
      float s = valid ? sacc[t][j] * 0.125f : -1e30f;
      sacc[t][j] = s;
      mx = fmaxf(mx, s);
    }
  }
  mx = fmaxf(mx, __shfl_xor(mx, 16));
  mx = fmaxf(mx, __shfl_xor(mx, 32));
  float sum = 0.f;
#pragma unroll
  for (int t = 0; t < 9; ++t)
#pragma unroll
    for (int j = 0; j < 4; ++j) {
      float e = __expf(sacc[t][j] - mx);
      sacc[t][j] = e;
      sum += e;
    }
  sum += __shfl_xor(sum, 16);
  sum += __shfl_xor(sum, 32);
  const float inv = 1.0f / sum;

  const int prow = w * 16 + (lane & 15);
#pragma unroll
  for (int t = 0; t < 9; ++t) {
    int c0 = jb + t * 16 + rj;
    unsigned int p0 = ftobf(sacc[t][0] * inv) |
                      ((unsigned int)ftobf(sacc[t][1] * inv) << 16);
    unsigned int p1 = ftobf(sacc[t][2] * inv) |
                      ((unsigned int)ftobf(sacc[t][3] * inv) << 16);
    *(unsigned int*)&Ps[swzW(prow, c0)] = p0;
    *(unsigned int*)&Ps[swzW(prow, c0 + 2)] = p1;
  }
  {
    int g2 = (lane >> 4) * 2;
    for (int col = g2; col < jb; col += 8)
      *(unsigned int*)&Ps[swzW(prow, col)] = 0;
    for (int col = jb + 144 + g2; col < 192; col += 8)
      *(unsigned int*)&Ps[swzW(prow, col)] = 0;
  }
  f32x4 oacc[4] = {};
#pragma unroll
  for (int kb = 0; kb < 6; ++kb) {
    short8 pa = *(const short8*)&Ps[swzW(prow, kb * 32 + kg8)];
#pragma unroll
    for (int dt = 0; dt < 4; ++dt) {
      short8 vb = *(const short8*)&Vt[swzW(dt * 16 + (lane & 15), kb * 32 + kg8)];
      oacc[dt] = __builtin_amdgcn_mfma_f32_16x16x32_bf16(pa, vb, oacc[dt], 0, 0, 0);
    }
  }
  const int cj = lane & 15;
#pragma unroll
  for (int j = 0; j < 4; ++j)
#pragma unroll
    for (int dt = 0; dt < 4; ++dt)
      o[(size_t)(b * Sc + q0 + w * 16 + rj + j) * Dc + hh * DHc + dt * 16 + cj] =
          ftobf(oacc[dt][j]);
}

// ---------------------------------------------------------------------------
// LayerNorm over D=512, one wave per token; fp32 + bf16 outputs.
// ---------------------------------------------------------------------------
__global__ __launch_bounds__(256) void k_ln(const float* __restrict__ in,
                                            const float* __restrict__ g,
                                            const float* __restrict__ bta,
                                            float* __restrict__ out,
                                            unsigned short* __restrict__ outb) {
  const int wid = threadIdx.x >> 6;
  const int lane = threadIdx.x & 63;
  const int t = blockIdx.x * 4 + wid;
  const float* row = in + (size_t)t * Dc;
  float v[8];
  float sum = 0.0f, sq = 0.0f;
#pragma unroll
  for (int i = 0; i < 8; ++i) {
    float xv = row[lane + i * 64];
    v[i] = xv;
    sum += xv;
    sq += xv * xv;
  }
#pragma unroll
  for (int off = 32; off; off >>= 1) {
    sum += __shfl_xor(sum, off);
    sq += __shfl_xor(sq, off);
  }
  float m = sum * (1.0f / 512.0f);
  float var = sq * (1.0f / 512.0f) - m * m;
  float rstd = rsqrtf(var + 1e-5f);
#pragma unroll
  for (int i = 0; i < 8; ++i) {
    int d = lane + i * 64;
    float ov = (v[i] - m) * rstd * g[d] + bta[d];
    out[(size_t)t * Dc + d] = ov;
    outb[(size_t)t * Dc + d] = ftobf(ov);
  }
}

// ---------------------------------------------------------------------------
// Head (fp32): mu | clipped log_sigma
// ---------------------------------------------------------------------------
__global__ __launch_bounds__(256) void k_head(const float* __restrict__ h,
                                              const float* __restrict__ Wh,
                                              const float* __restrict__ bh,
                                              float* __restrict__ outp) {
  const int wid = threadIdx.x >> 6;
  const int lane = threadIdx.x & 63;
  const int t = blockIdx.x * 4 + wid;
  const float* row = h + (size_t)t * Dc;
  float a0 = 0, a1 = 0, a2 = 0, a3 = 0;
#pragma unroll
  for (int i = 0; i < 8; ++i) {
    int d = lane + i * 64;
    float xv = row[d];
    a0 += xv * Wh[0 * Dc + d];
    a1 += xv * Wh[1 * Dc + d];
    a2 += xv * Wh[2 * Dc + d];
    a3 += xv * Wh[3 * Dc + d];
  }
#pragma unroll
  for (int off = 32; off; off >>= 1) {
    a0 += __shfl_xor(a0, off);
    a1 += __shfl_xor(a1, off);
    a2 += __shfl_xor(a2, off);
    a3 += __shfl_xor(a3, off);
  }
  if (lane == 0) {
    outp[(size_t)t * 2 + 0] = a0 + bh[0];
    outp[(size_t)t * 2 + 1] = a1 + bh[1];
    outp[(size_t)Tc * 2 + (size_t)t * 2 + 0] = fminf(fmaxf(a2 + bh[2], -6.0f), 1.5f);
    outp[(size_t)Tc * 2 + (size_t)t * 2 + 1] = fminf(fmaxf(a3 + bh[3], -6.0f), 1.5f);
  }
}

// ---------------------------------------------------------------------------
extern "C" void kernel_launch(void* const* d_in, const int* in_sizes, int n_in,
                              void* d_out, int out_size, void* d_ws, size_t ws_size,
                              hipStream_t stream) {
  const float* x    = (const float*)d_in[0];
  const float* W_in = (const float*)d_in[1];
  const float* b_in = (const float*)d_in[2];
  const float* pos  = (const float*)d_in[3];
  const float* Wqkv = (const float*)d_in[4];
  const float* bqkv = (const float*)d_in[5];
  const float* Wo   = (const float*)d_in[6];
  const float* bo   = (const float*)d_in[7];
  const float* W1   = (const float*)d_in[8];
  const float* b1   = (const float*)d_in[9];
  const float* W2   = (const float*)d_in[10];
  const float* b2   = (const float*)d_in[11];
  const float* ln1g = (const float*)d_in[12];
  const float* ln1b = (const float*)d_in[13];
  const float* ln2g = (const float*)d_in[14];
  const float* ln2b = (const float*)d_in[15];
  const float* Wh   = (const float*)d_in[16];
  const float* bh   = (const float*)d_in[17];
  float* out = (float*)d_out;

  char* p = (char*)d_ws;
  float* h  = (float*)p;           p += (size_t)Tc * Dc * 4;
  float* t2 = (float*)p;           p += (size_t)Tc * Dc * 4;
  unsigned short* hb  = (unsigned short*)p; p += (size_t)Tc * Dc * 2;
  unsigned short* ob  = (unsigned short*)p; p += (size_t)Tc * Dc * 2;
  unsigned short* big = (unsigned short*)p; p += (size_t)Tc * DFFc * 2;
  unsigned short* wqb = (unsigned short*)p; p += (size_t)Lc * QKVW * Dc * 2;
  unsigned short* wob = (unsigned short*)p; p += (size_t)Lc * Dc * Dc * 2;
  unsigned short* w1b = (unsigned short*)p; p += (size_t)Lc * DFFc * Dc * 2;
  unsigned short* w2b = (unsigned short*)p; p += (size_t)Lc * Dc * DFFc * 2;

  k_f2bf<<<Lc * QKVW * Dc / 256, 256, 0, stream>>>(Wqkv, wqb, Lc * QKVW * Dc);
  k_f2bf<<<Lc * Dc * Dc / 256, 256, 0, stream>>>(Wo, wob, Lc * Dc * Dc);
  k_f2bf<<<Lc * DFFc * Dc / 256, 256, 0, stream>>>(W1, w1b, Lc * DFFc * Dc);
  k_f2bf<<<Lc * Dc * DFFc / 256, 256, 0, stream>>>(W2, w2b, Lc * Dc * DFFc);

  k_embed<<<(Tc * Dc) / 256, 256, 0, stream>>>(x, W_in, b_in, pos, h, hb);

  for (int l = 0; l < Lc; ++l) {
    const unsigned short* wq_l = wqb + (size_t)l * QKVW * Dc;
    const unsigned short* wo_l = wob + (size_t)l * Dc * Dc;
    const unsigned short* w1_l = w1b + (size_t)l * DFFc * Dc;
    const unsigned short* w2_l = w2b + (size_t)l * Dc * DFFc;

    k_mgemm<0, 1><<<dim3(QKVW / 128, Tc / 128), 256, 0, stream>>>(
        hb, wq_l, bqkv + (size_t)l * QKVW, nullptr, big, Tc, QKVW, Dc);

    k_attn<<<Bc * Hc * (Sc / 64), 256, 0, stream>>>(big, ob);

    k_mgemm<1, 0><<<dim3(Dc / 128, Tc / 128), 256, 0, stream>>>(
        ob, wo_l, bo + (size_t)l * Dc, h, t2, Tc, Dc, Dc);

    k_ln<<<Tc / 4, 256, 0, stream>>>(t2, ln1g + (size_t)l * Dc, ln1b + (size_t)l * Dc, h, hb);

    k_mgemm<2, 1><<<dim3(DFFc / 128, Tc / 128), 256, 0, stream>>>(
        hb, w1_l, b1 + (size_t)l * DFFc, nullptr, big, Tc, DFFc, Dc);

    k_mgemm<1, 0><<<dim3(Dc / 128, Tc / 128), 256, 0, stream>>>(
        big, w2_l, b2 + (size_t)l * Dc, h, t2, Tc, Dc, DFFc);

    k_ln<<<Tc / 4, 256, 0, stream>>>(t2, ln2g + (size_t)l * Dc, ln2b + (size_t)l * Dc, h, hb);
  }

  k_head<<<Tc / 4, 256, 0, stream>>>(h, Wh, bh, out);
}